// Round 10
// baseline (567.266 us; speedup 1.0000x reference)
//
#include <hip/hip_runtime.h>
#include <math.h>

#define T_BATCH 128
#define N_TOK   256
#define C_DIM   1408
#define CN1     16
#define KNN1    8
#define CN2     6
#define KNN2    3
#define NOUT    22   // CN2 + CN1

typedef __attribute__((ext_vector_type(4))) short sh4;
typedef __attribute__((ext_vector_type(8))) short sh8;
typedef __attribute__((ext_vector_type(4))) float f32x4;
typedef __fp16 h2v __attribute__((ext_vector_type(2)));
typedef __fp16 h8v __attribute__((ext_vector_type(8)));

union h2u { h2v h; unsigned u; };
union h8pack { unsigned u[4]; h8v h; };

// f16 two-term split of a PAIR of fp32 -> packed f16 hi pair + f16 lo pair.
__device__ inline void split2(float v0, float v1, unsigned& hip, unsigned& lop) {
    h2v h = __builtin_amdgcn_cvt_pkrtz(v0, v1);
    float r0 = v0 - (float)h[0];
    float r1 = v1 - (float)h[1];
    h2v l = __builtin_amdgcn_cvt_pkrtz(r0, r1);
    h2u uh, ul;
    uh.h = h; ul.h = l;
    hip = uh.u;
    lop = ul.u;
}

// convert 8 consecutive floats (2 float4) to hi/lo f16 fragments + norm accum
__device__ inline void cvt8(const float4 u, const float4 v, h8v& hi, h8v& lo, float& nrm) {
    nrm += u.x * u.x + u.y * u.y + u.z * u.z + u.w * u.w
         + v.x * v.x + v.y * v.y + v.z * v.z + v.w * v.w;
    h8pack ph, pl;
    split2(u.x, u.y, ph.u[0], pl.u[0]);
    split2(u.z, u.w, ph.u[1], pl.u[1]);
    split2(v.x, v.y, ph.u[2], pl.u[2]);
    split2(v.z, v.w, ph.u[3], pl.u[3]);
    hi = ph.h;
    lo = pl.h;
}

// branchless insert of v into ascending 8-list m (keeps 8 smallest)
#define INS8(m, v) {                                   \
    float _x = (v);                                    \
    _Pragma("unroll")                                  \
    for (int _q = 0; _q < 8; _q++) {                   \
        float _lo = fminf(m[_q], _x);                  \
        _x = fmaxf(m[_q], _x);                         \
        m[_q] = _lo;                                   \
    }                                                  \
}

// ---------------------------------------------------------------------------
// Kernel A: dist via f16x3 MFMA, 64x64 tiles, upper-tri pairs only.
// BARRIER-FREE K-loop: each wave loads its OWN MFMA fragment rows directly
// from global (lane l: row fr=l&15, k-chunk fq=l>>4) and converts in
// registers — no LDS staging, no __syncthreads in the loop. Each row is
// read by 2 waves (partner re-read is L1/L2-hot within the K-step).
// Row norms via shfl_xor(16,32) + one small LDS exchange after the loop.
// Grid 1280 XCD-swizzled, 256 thr, tri tiles, epilogue identical to r9-best.
// ---------------------------------------------------------------------------
__global__ __launch_bounds__(256, 4) void gemm_dist_reg(const float* __restrict__ x,
                                                        float* __restrict__ dist) {
    const int id = blockIdx.x;
    const int r  = id & 7;
    const int q8 = id >> 3;          // 0..159
    const int p  = q8 % 10;
    const int tt = q8 / 10;          // 0..15
    const int t  = tt * 8 + r;
    const int bi = (p < 4) ? 0 : (p < 7) ? 1 : (p < 9) ? 2 : 3;
    const int bj = (p < 4) ? p : (p < 7) ? p - 3 : (p < 9) ? p - 5 : 3;
    const int i0 = bi * 64, j0 = bj * 64;
    const bool diag = (bi == bj);
    const float* X = x + (size_t)t * N_TOK * C_DIM;

    __shared__ float snA[64], snB[64];

    const int tid  = threadIdx.x;
    const int wave = tid >> 6;
    const int lane = tid & 63;
    const int qr   = wave >> 1;
    const int qc   = wave & 1;
    const int fr   = lane & 15;
    const int fq   = lane >> 4;

    f32x4 acc[2][2];
#pragma unroll
    for (int a = 0; a < 2; a++)
#pragma unroll
        for (int b = 0; b < 2; b++) acc[a][b] = (f32x4){0.f, 0.f, 0.f, 0.f};

    // per-lane fragment-row pointers (lane owns row fr of each 16-row group,
    // k-chunk fq*8 within each 32-float K-step)
    const float* pA0 = X + (size_t)(i0 + qr * 32 + fr) * C_DIM + fq * 8;
    const float* pA1 = pA0 + (size_t)16 * C_DIM;
    const float* pB0 = X + (size_t)(j0 + qc * 32 + fr) * C_DIM + fq * 8;
    const float* pB1 = pB0 + (size_t)16 * C_DIM;
    float nA0 = 0.f, nA1 = 0.f, nB0 = 0.f, nB1 = 0.f;

    // prologue: K-step 0 loads
    float4 a00 = *(const float4*)(pA0);
    float4 a01 = *(const float4*)(pA0 + 4);
    float4 a10 = *(const float4*)(pA1);
    float4 a11 = *(const float4*)(pA1 + 4);
    float4 b00 = *(const float4*)(pB0);
    float4 b01 = *(const float4*)(pB0 + 4);
    float4 b10 = *(const float4*)(pB1);
    float4 b11 = *(const float4*)(pB1 + 4);

    for (int k0 = 0; k0 < C_DIM; k0 += 32) {
        // convert current regs -> fragments
        h8v fAh[2], fAl[2], fBh[2], fBl[2];
        cvt8(a00, a01, fAh[0], fAl[0], nA0);
        cvt8(a10, a11, fAh[1], fAl[1], nA1);
        cvt8(b00, b01, fBh[0], fBl[0], nB0);
        cvt8(b10, b11, fBh[1], fBl[1], nB1);

        // T14: issue next K-step's loads before the MFMA block
        const int k1 = k0 + 32;
        if (k1 < C_DIM) {
            a00 = *(const float4*)(pA0 + k1);
            a01 = *(const float4*)(pA0 + k1 + 4);
            a10 = *(const float4*)(pA1 + k1);
            a11 = *(const float4*)(pA1 + k1 + 4);
            b00 = *(const float4*)(pB0 + k1);
            b01 = *(const float4*)(pB0 + k1 + 4);
            b10 = *(const float4*)(pB1 + k1);
            b11 = *(const float4*)(pB1 + k1 + 4);
        }

#pragma unroll
        for (int mt = 0; mt < 2; mt++)
#pragma unroll
            for (int nt = 0; nt < 2; nt++) {
                acc[mt][nt] = __builtin_amdgcn_mfma_f32_16x16x32_f16(fAh[mt], fBh[nt], acc[mt][nt], 0, 0, 0);
                acc[mt][nt] = __builtin_amdgcn_mfma_f32_16x16x32_f16(fAh[mt], fBl[nt], acc[mt][nt], 0, 0, 0);
                acc[mt][nt] = __builtin_amdgcn_mfma_f32_16x16x32_f16(fAl[mt], fBh[nt], acc[mt][nt], 0, 0, 0);
            }
    }

    // ---- row norms: sum the 4 k-chunk lanes (same fr, fq=0..3) ----
    nA0 += __shfl_xor(nA0, 16); nA0 += __shfl_xor(nA0, 32);
    nA1 += __shfl_xor(nA1, 16); nA1 += __shfl_xor(nA1, 32);
    nB0 += __shfl_xor(nB0, 16); nB0 += __shfl_xor(nB0, 32);
    nB1 += __shfl_xor(nB1, 16); nB1 += __shfl_xor(nB1, 32);
    if (fq == 0 && qc == 0) {
        snA[qr * 32 + fr]      = nA0;
        snA[qr * 32 + 16 + fr] = nA1;
    }
    if (fq == 0 && qr == 0) {
        snB[qc * 32 + fr]      = nB0;
        snB[qc * 32 + 16 + fr] = nB1;
    }
    __syncthreads();

    const float inv_sqrtC = 1.0f / sqrtf((float)C_DIM);
    float* Dt = dist + (size_t)t * N_TOK * N_TOK;
#pragma unroll
    for (int mt = 0; mt < 2; mt++)
#pragma unroll
        for (int nt = 0; nt < 2; nt++) {
            int jl = qc * 32 + nt * 16 + fr;
            int jg = j0 + jl;
            float sqj = snB[jl];
            int il0 = qr * 32 + mt * 16 + fq * 4;
            float vv[4];
#pragma unroll
            for (int rr = 0; rr < 4; rr++) {
                int ig = i0 + il0 + rr;
                float d2 = snA[il0 + rr] + sqj - 2.0f * acc[mt][nt][rr];
                float v = (ig == jg) ? 0.0f : sqrtf(fmaxf(d2, 0.0f)) * inv_sqrtC;
                Dt[(size_t)ig * N_TOK + jg] = v;
                vv[rr] = v;
            }
            if (!diag) {
                float4 o; o.x = vv[0]; o.y = vv[1]; o.z = vv[2]; o.w = vv[3];
                *(float4*)&Dt[(size_t)jg * N_TOK + i0 + il0] = o;
            }
        }
}

// ---------------------------------------------------------------------------
// Kernel B: fused layer-1 DPC. 1024 threads/block, one block per batch.
// 4 threads per column (64-row quarter scans), 2 chains each, LDS merge.
// ---------------------------------------------------------------------------
__global__ __launch_bounds__(1024) void dpc1_fused(const float* __restrict__ dist,
                                                   int* __restrict__ memb,
                                                   int* __restrict__ cntg,
                                                   int* __restrict__ offg) {
    const int t    = blockIdx.x;
    const int tid  = threadIdx.x;    // 0..1023
    const int col  = tid & 255;
    const int h    = tid >> 8;       // row quarter 0..3
    const int lane = tid & 63;
    const int wid  = tid >> 6;       // 0..15
    const float* D = dist + (size_t)t * N_TOK * N_TOK;

    __shared__ float dens_s[N_TOK];
    __shared__ float lists[KNN1][1024];
    __shared__ float red[1024];
    __shared__ float rmax16[16];
    __shared__ unsigned long long wred[16];
    __shared__ int centers[CN1];
    __shared__ int bks[N_TOK];
    __shared__ int cnt_s[CN1], off_s[CN1];

    // ---- pass 1: 8 smallest of this quarter-column, 2 chains ----
    float c0[8], c1[8];
#pragma unroll
    for (int q = 0; q < 8; q++) { c0[q] = 3.4e38f; c1[q] = 3.4e38f; }
    float mx = 0.f;
    const float* base = D + (size_t)(h * 64) * N_TOK + col;
    for (int jj = 0; jj < 64; jj += 2) {
        float d0 = base[(size_t)(jj + 0) * N_TOK];
        float d1 = base[(size_t)(jj + 1) * N_TOK];
        mx = fmaxf(mx, fmaxf(d0, d1));
        INS8(c0, d0); INS8(c1, d1);
    }
#pragma unroll
    for (int q = 0; q < 8; q++) { INS8(c0, c1[q]); }
#pragma unroll
    for (int q = 0; q < 8; q++) lists[q][tid] = c0[q];
    // dmax: wave shuffle-reduce, then 16-entry LDS
#pragma unroll
    for (int off = 32; off > 0; off >>= 1) mx = fmaxf(mx, __shfl_xor(mx, off));
    if (lane == 0) rmax16[wid] = mx;
    __syncthreads();
    float dmax = rmax16[0];
#pragma unroll
    for (int w = 1; w < 16; w++) dmax = fmaxf(dmax, rmax16[w]);

    if (h == 0) {
#pragma unroll
        for (int s = 1; s < 4; s++)
#pragma unroll
            for (int q = 0; q < 8; q++) { float v = lists[q][col + s * 256]; INS8(c0, v); }
        float s2 = 0.f;
#pragma unroll
        for (int q = 0; q < 8; q++) s2 += c0[q] * c0[q];
        dens_s[col] = expf(-s2 / (float)KNN1);
    }
    __syncthreads();
    const float dens = dens_s[col];

    // ---- pass 2: parent distance over this quarter, 2 chains ----
    float p0 = dmax, p1 = dmax;
    const float* dsh = dens_s + h * 64;
    for (int jj = 0; jj < 64; jj += 2) {
        float d0 = base[(size_t)(jj + 0) * N_TOK];
        float d1 = base[(size_t)(jj + 1) * N_TOK];
        p0 = (dsh[jj + 0] > dens) ? fminf(p0, d0) : p0;
        p1 = (dsh[jj + 1] > dens) ? fminf(p1, d1) : p1;
    }
    red[tid] = fminf(p0, p1);
    __syncthreads();
    float score = 0.f;
    if (h == 0)
        score = fminf(fminf(red[col], red[col + 256]),
                      fminf(red[col + 512], red[col + 768])) * dens;

    // ---- top-16 (desc, ties -> lowest index) ----
    unsigned long long key = 0;
    if (h == 0)
        key = ((unsigned long long)__float_as_uint(score) << 32) | (unsigned)(65535 - col);
    for (int k = 0; k < CN1; k++) {
        unsigned long long mm = key;
#pragma unroll
        for (int off = 32; off > 0; off >>= 1) {
            unsigned long long o = __shfl_xor(mm, off);
            mm = (o > mm) ? o : mm;
        }
        if (lane == 0) wred[wid] = mm;
        __syncthreads();
        unsigned long long b = wred[0];
#pragma unroll
        for (int w = 1; w < 16; w++) b = (wred[w] > b) ? wred[w] : b;
        int idx = 65535 - (int)(b & 0xFFFFull);
        if (tid == 0) centers[k] = idx;
        if (tid == idx) key = 0;
        __syncthreads();
    }

    // ---- assign + member lists (h==0 threads; barriers unconditional) ----
    int bk = 0;
    if (h == 0) {
        float bd = 3.4e38f;
#pragma unroll
        for (int k = 0; k < CN1; k++) {
            float d = D[(size_t)centers[k] * N_TOK + col];
            if (d < bd) { bd = d; bk = k; }
        }
#pragma unroll
        for (int k = 0; k < CN1; k++) if (col == centers[k]) bk = k;
        bks[col] = bk;
    }
    __syncthreads();
    if (tid < CN1) {
        int c = 0;
        for (int j = 0; j < N_TOK; j++) c += (bks[j] == tid);
        cnt_s[tid] = c;
    }
    __syncthreads();
    if (tid == 0) {
        int o = 0;
        for (int q = 0; q < CN1; q++) { off_s[q] = o; o += cnt_s[q]; }
    }
    __syncthreads();
    if (h == 0) {
        int rank = 0;
        for (int j = 0; j < col; j++) rank += (bks[j] == bk);
        memb[t * N_TOK + off_s[bk] + rank] = col;
    }
    if (tid < CN1) {
        cntg[t * CN1 + tid] = cnt_s[tid];
        offg[t * CN1 + tid] = off_s[tid];
    }
}

// ---------------------------------------------------------------------------
// Kernel C: merge1 via member lists, member loop unrolled x4 (4 independent
// row streams in flight; summation order preserved).
// ---------------------------------------------------------------------------
__global__ __launch_bounds__(256) void merge1_kernel(const float* __restrict__ x,
                                                     const int* __restrict__ memb,
                                                     const int* __restrict__ cntg,
                                                     const int* __restrict__ offg,
                                                     float* __restrict__ meta1) {
    const int q   = blockIdx.x;
    const int t   = blockIdx.y;
    const int tid = threadIdx.x;
    const int n    = cntg[t * CN1 + q];
    const int base = t * N_TOK + offg[t * CN1 + q];
    const int c0 = tid, c1 = tid + 256;
    const bool act1 = (c1 < C_DIM / 4);
    const float4* xb = (const float4*)(x + (size_t)t * N_TOK * C_DIM);
    const int stride4 = C_DIM / 4;

    float4 s0 = {0.f, 0.f, 0.f, 0.f};
    float4 s1 = {0.f, 0.f, 0.f, 0.f};
    int m = 0;
    for (; m + 4 <= n; m += 4) {
        int r0 = memb[base + m + 0];
        int r1 = memb[base + m + 1];
        int r2 = memb[base + m + 2];
        int r3 = memb[base + m + 3];
        float4 a0 = xb[(size_t)r0 * stride4 + c0];
        float4 a1 = xb[(size_t)r1 * stride4 + c0];
        float4 a2 = xb[(size_t)r2 * stride4 + c0];
        float4 a3 = xb[(size_t)r3 * stride4 + c0];
        s0.x += a0.x; s0.y += a0.y; s0.z += a0.z; s0.w += a0.w;
        s0.x += a1.x; s0.y += a1.y; s0.z += a1.z; s0.w += a1.w;
        s0.x += a2.x; s0.y += a2.y; s0.z += a2.z; s0.w += a2.w;
        s0.x += a3.x; s0.y += a3.y; s0.z += a3.z; s0.w += a3.w;
        if (act1) {
            float4 b0 = xb[(size_t)r0 * stride4 + c1];
            float4 b1 = xb[(size_t)r1 * stride4 + c1];
            float4 b2 = xb[(size_t)r2 * stride4 + c1];
            float4 b3 = xb[(size_t)r3 * stride4 + c1];
            s1.x += b0.x; s1.y += b0.y; s1.z += b0.z; s1.w += b0.w;
            s1.x += b1.x; s1.y += b1.y; s1.z += b1.z; s1.w += b1.w;
            s1.x += b2.x; s1.y += b2.y; s1.z += b2.z; s1.w += b2.w;
            s1.x += b3.x; s1.y += b3.y; s1.z += b3.z; s1.w += b3.w;
        }
    }
    for (; m < n; m++) {
        int r0 = memb[base + m];
        float4 a0 = xb[(size_t)r0 * stride4 + c0];
        s0.x += a0.x; s0.y += a0.y; s0.z += a0.z; s0.w += a0.w;
        if (act1) {
            float4 b0 = xb[(size_t)r0 * stride4 + c1];
            s1.x += b0.x; s1.y += b0.y; s1.z += b0.z; s1.w += b0.w;
        }
    }
    float w = 1.0f / ((float)n + 1e-6f);
    float4* mr = (float4*)(meta1 + ((size_t)t * CN1 + q) * C_DIM);
    float4 o0; o0.x = s0.x * w; o0.y = s0.y * w; o0.z = s0.z * w; o0.w = s0.w * w;
    mr[c0] = o0;
    if (act1) {
        float4 o1; o1.x = s1.x * w; o1.y = s1.y * w; o1.z = s1.z * w; o1.w = s1.w * w;
        mr[c1] = o1;
    }
}

// ---------------------------------------------------------------------------
// Kernel DE: layer-2 DPC + merge2 + modulation + grouped output.
// Grid 256 = 2 blocks per batch: twins redundantly compute the cheap phases
// (deterministic, identical results) and split the output phase by channel half.
// ---------------------------------------------------------------------------
__global__ __launch_bounds__(1024) void layer2_kernel(const float* __restrict__ meta1,
                                                      const float* __restrict__ score_w,
                                                      const float* __restrict__ score_b,
                                                      float* __restrict__ out) {
    const int t   = blockIdx.x & 127;   // batch
    const int bh  = blockIdx.x >> 7;    // channel half 0/1
    const int tid = threadIdx.x;        // 0..1023
    const float* M = meta1 + (size_t)t * CN1 * C_DIM;

    __shared__ float buf[CN1][132];
    __shared__ float d2s[CN1][CN1];
    __shared__ float m2[CN2][C_DIM];
    __shared__ float dens[CN1], scor[CN1], nrm[CN1], rmx[CN1];
    __shared__ int   centers[CN2], idx2s[CN1], cnt2[CN2];
    __shared__ float modu[CN2], msum[CN2];
    __shared__ int   srcRow[NOUT], cidArr[NOUT];
    __shared__ float dmax_sh;

    const int ti = (tid < 256) ? (tid >> 4) : 0;
    const int tj = tid & 15;

    // ---- pairwise dots (threads 0-255 own one (i,j) pair; all stage) ----
    float acc = 0.f;
    for (int c0 = 0; c0 < C_DIM; c0 += 128) {
        for (int e = tid; e < CN1 * 128; e += 1024) {
            int r = e >> 7, c = e & 127;
            buf[r][c] = M[(size_t)r * C_DIM + c0 + c];
        }
        __syncthreads();
        if (tid < 256) {
#pragma unroll
            for (int cc = 0; cc < 128; cc += 4) {
                float4 a = *(const float4*)&buf[ti][cc];
                float4 b = *(const float4*)&buf[tj][cc];
                acc += a.x * b.x + a.y * b.y + a.z * b.z + a.w * b.w;
            }
        }
        __syncthreads();
    }
    if (tid < 256 && ti == tj) nrm[ti] = acc;
    __syncthreads();

    const float inv_sqrtC = 1.0f / sqrtf((float)C_DIM);
    if (tid < 256) {
        float d2 = nrm[ti] + nrm[tj] - 2.f * acc;
        d2s[ti][tj] = sqrtf(fmaxf(d2, 0.f)) * inv_sqrtC;
    }
    __syncthreads();

    if (tid < CN1) {
        float m0 = 3.4e38f, m1 = 3.4e38f, m2v = 3.4e38f, mx = 0.f;
        for (int j = 0; j < CN1; j++) {
            float d = d2s[tid][j];
            mx = fmaxf(mx, d);
            if (d < m2v) {
                m2v = d;
                if (m2v < m1) { float tmp = m2v; m2v = m1; m1 = tmp; }
                if (m1 < m0)  { float tmp = m1;  m1 = m0;  m0 = tmp; }
            }
        }
        dens[tid] = expf(-(m0 * m0 + m1 * m1 + m2v * m2v) / (float)KNN2);
        rmx[tid] = mx;
    }
    __syncthreads();
    if (tid == 0) {
        float g = 0.f;
        for (int j = 0; j < CN1; j++) g = fmaxf(g, rmx[j]);
        dmax_sh = g;
    }
    __syncthreads();

    if (tid < CN1) {
        float di = dens[tid];
        float pd = dmax_sh;
        for (int j = 0; j < CN1; j++)
            if (dens[j] > di) pd = fminf(pd, d2s[tid][j]);
        scor[tid] = pd * di;
    }
    __syncthreads();

    if (tid == 0) {
        for (int k = 0; k < CN2; k++) {
            float best = -3.4e38f; int bi = 0;
            for (int j = 0; j < CN1; j++)
                if (scor[j] > best) { best = scor[j]; bi = j; }
            centers[k] = bi;
            scor[bi] = -3.4e38f;
        }
    }
    __syncthreads();

    if (tid < CN1) {
        float bd = 3.4e38f; int bk = 0;
#pragma unroll
        for (int k = 0; k < CN2; k++) {
            float d = d2s[centers[k]][tid];
            if (d < bd) { bd = d; bk = k; }
        }
#pragma unroll
        for (int k = 0; k < CN2; k++) if (tid == centers[k]) bk = k;
        idx2s[tid] = bk;
    }
    __syncthreads();

    if (tid == 0) {
        for (int v = 0; v < CN2; v++) cnt2[v] = 0;
        for (int i = 0; i < CN1; i++) cnt2[idx2s[i]]++;
        int slot = 0;
        for (int v = 0; v < CN2; v++) {
            srcRow[slot] = CN1 + v; cidArr[slot] = v; slot++;
            for (int i = 0; i < CN1; i++)
                if (idx2s[i] == v) { srcRow[slot] = i; cidArr[slot] = v; slot++; }
        }
        for (int v = 0; v < CN2; v++) msum[v] = 0.f;
    }
    __syncthreads();

    // ---- meta2 scatter-mean + channel sums (full C_DIM in both twins:
    //      msum must cover all channels for the modulation softmax) ----
    float ls[CN2] = {0.f, 0.f, 0.f, 0.f, 0.f, 0.f};
    for (int ch = tid; ch < C_DIM; ch += 1024) {
        float a6[CN2] = {0.f, 0.f, 0.f, 0.f, 0.f, 0.f};
        for (int r = 0; r < CN1; r++) {
            float v = M[(size_t)r * C_DIM + ch];
            int c = idx2s[r];
#pragma unroll
            for (int q = 0; q < CN2; q++) a6[q] += (c == q) ? v : 0.f;
        }
#pragma unroll
        for (int q = 0; q < CN2; q++) {
            float mv = a6[q] / ((float)cnt2[q] + 1e-6f);
            m2[q][ch] = mv;
            ls[q] += mv;
        }
    }
#pragma unroll
    for (int q = 0; q < CN2; q++) atomicAdd(&msum[q], ls[q]);
    __syncthreads();

    if (tid == 0) {
        float mean[CN2], lg[CN2];
        for (int v = 0; v < CN2; v++) mean[v] = msum[v] / (float)C_DIM;
        float mxl = -3.4e38f;
        for (int u = 0; u < CN2; u++) {
            float s = score_b[u];
            for (int v = 0; v < CN2; v++) s += mean[v] * score_w[u * CN2 + v];
            lg[u] = s;
            mxl = fmaxf(mxl, s);
        }
        float den = 0.f;
        for (int u = 0; u < CN2; u++) { lg[u] = expf(lg[u] - mxl); den += lg[u]; }
        for (int u = 0; u < CN2; u++) modu[u] = lg[u] / den;
    }
    __syncthreads();

    // ---- grouped, scaled output: this block writes channel half bh ----
    const int chLo = bh * (C_DIM / 2);
    const int chHi = chLo + (C_DIM / 2);
    float* ob = out + (size_t)t * NOUT * C_DIM;
    for (int ch = chLo + tid; ch < chHi; ch += 1024) {
#pragma unroll
        for (int s = 0; s < NOUT; s++) {
            int r = srcRow[s];
            float v = (r < CN1) ? M[(size_t)r * C_DIM + ch] : m2[r - CN1][ch];
            ob[(size_t)s * C_DIM + ch] = v * modu[cidArr[s]];
        }
    }
}

// ---------------------------------------------------------------------------
extern "C" void kernel_launch(void* const* d_in, const int* in_sizes, int n_in,
                              void* d_out, int out_size, void* d_ws, size_t ws_size,
                              hipStream_t stream) {
    const float* x  = (const float*)d_in[0];   // [128,256,1408]
    const float* sw = (const float*)d_in[1];   // [6,6]
    const float* sb = (const float*)d_in[2];   // [6]
    float* out = (float*)d_out;                // [128,22,1408]

    float* ws     = (float*)d_ws;
    float* dist   = ws;                                          // 8,388,608 f
    float* meta1  = dist + (size_t)T_BATCH * N_TOK * N_TOK;      // 2,883,584 f
    int*   memb   = (int*)(meta1 + (size_t)T_BATCH * CN1 * C_DIM); // 32768 i
    int*   cntg   = memb + (size_t)T_BATCH * N_TOK;              // 2048 i
    int*   offg   = cntg + T_BATCH * CN1;                        // 2048 i

    gemm_dist_reg<<<1280, 256, 0, stream>>>(x, dist);
    dpc1_fused<<<T_BATCH, 1024, 0, stream>>>(dist, memb, cntg, offg);
    merge1_kernel<<<dim3(CN1, T_BATCH), 256, 0, stream>>>(x, memb, cntg, offg, meta1);
    layer2_kernel<<<2 * T_BATCH, 1024, 0, stream>>>(meta1, sw, sb, out);
}